// Round 6
// baseline (525.373 us; speedup 1.0000x reference)
//
#include <hip/hip_runtime.h>

namespace {

constexpr int B = 4, S = 4096, H = 16, D = 32;
constexpr int L = 32;             // chunk length
constexpr int NC = S / L;         // 128 chunks per sequence
constexpr int NBH = B * H;        // 64
constexpr int RS = H * D;         // 512 floats between consecutive time steps
constexpr int PW = 36;            // padded LDS row width (16B-aligned rows, conflict-free)
constexpr float GEPS = 1.52587890625e-05f;  // 2^-16 per-step decay clamp
                                            // (max 7 steps to sub-block end * 16 = 112 < 126)

__device__ __forceinline__ float flog2(float x) { return __builtin_amdgcn_logf(x); }
__device__ __forceinline__ float fexp2(float x) { return __builtin_amdgcn_exp2f(x); }

// ---------------- Kernel 1: per-chunk summaries ----------------
// l = cumsum log2(max(g,GEPS)); W_j[m] = v_j[m]*2^{l_end[m]-l_j[m]} (<=1)
// KVb[bh][c][d][m] = sum_j k_j[d]*W_j[m];  Gb[bh][c][m] = 2^{l_end[m]}
// Scan: column-parallel in LDS (3 barriers, no shuffles -> low VGPR).
__global__ __launch_bounds__(256, 8)
void k1_chunk_summary(const float* __restrict__ Kp, const float* __restrict__ Vp,
                      const float* __restrict__ Gp, float* __restrict__ KVb,
                      float* __restrict__ Gb)
{
    __shared__ float k_s[L][PW];
    __shared__ float w_s[L][PW];   // v at load; scaled to W in place
    __shared__ float lg[L][PW];    // per-row log2(gate)
    __shared__ float sub[8][D];    // 4-row group subtotals

    const int blk = blockIdx.x;
    const int bh = blk / NC, c = blk % NC;
    const int b = bh / H, h = bh % H;
    const long base = ((long)b * S + (long)c * L) * RS + h * D;

    const int tid = threadIdx.x;
    const int i = tid >> 3;          // row 0..31
    const int u = (tid & 7) * 4;     // col quad
    const long roff = base + (long)i * RS + u;

    float4 k4 = *(const float4*)(Kp + roff);
    float4 v4 = *(const float4*)(Vp + roff);
    float4 g4 = *(const float4*)(Gp + roff);
    *(float4*)&k_s[i][u] = k4;
    *(float4*)&w_s[i][u] = v4;
    float4 lv;
    lv.x = flog2(fmaxf(g4.x, GEPS));
    lv.y = flog2(fmaxf(g4.y, GEPS));
    lv.z = flog2(fmaxf(g4.z, GEPS));
    lv.w = flog2(fmaxf(g4.w, GEPS));
    *(float4*)&lg[i][u] = lv;
    __syncthreads();                               // b1

    // column scan: thread -> (column m, 4-row group t)
    const int m = tid & 31, t = tid >> 5;
    const int r0 = t * 4;
    float c0 = lg[r0 + 0][m];
    float c1 = c0 + lg[r0 + 1][m];
    float c2 = c1 + lg[r0 + 2][m];
    float c3 = c2 + lg[r0 + 3][m];
    sub[t][m] = c3;
    __syncthreads();                               // b2

    float sb[8];
    float total = 0.f;
    #pragma unroll
    for (int tt = 0; tt < 8; ++tt) { sb[tt] = sub[tt][m]; total += sb[tt]; }
    float base_l = 0.f;
    #pragma unroll
    for (int tt = 0; tt < 8; ++tt) { if (tt < t) base_l += sb[tt]; }
    // W = v * 2^{total - l}   (exponent <= 0)
    w_s[r0 + 0][m] *= fexp2(total - (base_l + c0));
    w_s[r0 + 1][m] *= fexp2(total - (base_l + c1));
    w_s[r0 + 2][m] *= fexp2(total - (base_l + c2));
    w_s[r0 + 3][m] *= fexp2(total - (base_l + c3));
    if (t == 0) Gb[(long)(bh * NC + c) * D + m] = fexp2(total);
    __syncthreads();                               // b3

    // KV[d][m] = sum_j k[j][d] * W[j][m]
    const int d = tid >> 3;
    const int mg = (tid & 7) * 4;
    float4 acc = {0, 0, 0, 0};
    #pragma unroll
    for (int j = 0; j < L; ++j) {
        float kv = k_s[j][d];
        float4 w = *(float4*)&w_s[j][mg];
        acc.x += kv * w.x; acc.y += kv * w.y; acc.z += kv * w.z; acc.w += kv * w.w;
    }
    *(float4*)(KVb + (long)(bh * NC + c) * (D * D) + d * D + mg) = acc;
}

// ---------------- Kernel 2: inter-chunk scan (in-place KV -> S0) ----------------
// 8-deep batched prefetch; all register indices static.
__global__ __launch_bounds__(256)
void k2_scan(float* __restrict__ KVb, const float* __restrict__ Gb)
{
    const int bh = blockIdx.x >> 2;
    const int dg = blockIdx.x & 3;
    const int tid = threadIdx.x;
    const int d = dg * 8 + (tid >> 5);
    const int m = tid & 31;

    const long kvoff = (long)bh * NC * (D * D) + d * D + m;
    const long goff = (long)bh * NC * D + m;

    float ka[8], ga[8];
    #pragma unroll
    for (int t = 0; t < 8; ++t) {
        ka[t] = KVb[kvoff + (long)t * (D * D)];
        ga[t] = Gb[goff + (long)t * D];
    }
    float st = 0.f;
    for (int c0 = 0; c0 < NC; c0 += 8) {
        float kb[8], gb2[8];
        const bool more = (c0 + 8) < NC;
        #pragma unroll
        for (int t = 0; t < 8; ++t) {
            kb[t]  = more ? KVb[kvoff + (long)(c0 + 8 + t) * (D * D)] : 0.f;
            gb2[t] = more ? Gb[goff + (long)(c0 + 8 + t) * D] : 0.f;
        }
        #pragma unroll
        for (int t = 0; t < 8; ++t) {
            KVb[kvoff + (long)(c0 + t) * (D * D)] = st;   // chunk-START state
            st = ga[t] * st + ka[t];
        }
        #pragma unroll
        for (int t = 0; t < 8; ++t) { ka[t] = kb[t]; ga[t] = gb2[t]; }
    }
}

// ---------------- Kernel 3: per-chunk outputs ----------------
// out_i[m] = 2^{l_i[m]}*(q_i.S0[:,m])
//          + sum_{s<=si} 2^{l_i[m]-e_s[m]} * sum_{j in s, j<=i} A_ij*W_j[m]
// W_j[m] = v_j[m]*2^{e_{s(j)}[m]-l_j[m]};  e_s = l at row 8s+7 (sub-block end).
// 3 barriers; S0 read directly from global (L1-resident, 8-lane broadcast).
__global__ __launch_bounds__(256, 7)
void k3_out(const float* __restrict__ Qp, const float* __restrict__ Kp,
            const float* __restrict__ Vp, const float* __restrict__ Gp,
            const float* __restrict__ S0b, float* __restrict__ Op)
{
    __shared__ float q_s[L][PW];
    __shared__ float kT[D][L + 1];
    __shared__ float w_s[L][PW];   // v at load; scaled to W in place
    __shared__ float l_s[L][PW];   // logs at load; overwritten with final l
    __shared__ float a_s[L][L + 1];
    __shared__ float sub[8][D];

    const int blk = blockIdx.x;
    const int bh = blk / NC, c = blk % NC;
    const int b = bh / H, h = bh % H;
    const long base = ((long)b * S + (long)c * L) * RS + h * D;

    const int tid = threadIdx.x;
    const int i = tid >> 3;
    const int u = (tid & 7) * 4;
    const int wv = i >> 3;           // sub-block id (wave-uniform)
    const long roff = base + (long)i * RS + u;

    float4 q4 = *(const float4*)(Qp + roff);
    float4 k4 = *(const float4*)(Kp + roff);
    float4 v4 = *(const float4*)(Vp + roff);
    float4 g4 = *(const float4*)(Gp + roff);

    *(float4*)&q_s[i][u] = q4;
    kT[u + 0][i] = k4.x; kT[u + 1][i] = k4.y;
    kT[u + 2][i] = k4.z; kT[u + 3][i] = k4.w;
    *(float4*)&w_s[i][u] = v4;
    float4 lv;
    lv.x = flog2(fmaxf(g4.x, GEPS));
    lv.y = flog2(fmaxf(g4.y, GEPS));
    lv.z = flog2(fmaxf(g4.z, GEPS));
    lv.w = flog2(fmaxf(g4.w, GEPS));
    *(float4*)&l_s[i][u] = lv;
    __syncthreads();                               // b1

    // --- phase A: column subtotals + A-matmul (independent work) ---
    const int m = tid & 31, t = tid >> 5;
    const int r0 = t * 4;
    float c0 = l_s[r0 + 0][m];
    float c1 = c0 + l_s[r0 + 1][m];
    float c2 = c1 + l_s[r0 + 2][m];
    float c3 = c2 + l_s[r0 + 3][m];
    sub[t][m] = c3;

    // A[i][u..u+3] = q_i . k_j (unmasked; consumers use j<=i only)
    {
        float4 a = {0, 0, 0, 0};
        #pragma unroll
        for (int dd = 0; dd < 8; ++dd) {
            float4 qd = *(float4*)&q_s[i][dd * 4];
            #pragma unroll
            for (int cc = 0; cc < 4; ++cc) {
                const float qv = (&qd.x)[cc];
                const int d = dd * 4 + cc;
                a.x += qv * kT[d][u + 0];
                a.y += qv * kT[d][u + 1];
                a.z += qv * kT[d][u + 2];
                a.w += qv * kT[d][u + 3];
            }
        }
        a_s[i][u + 0] = a.x; a_s[i][u + 1] = a.y;
        a_s[i][u + 2] = a.z; a_s[i][u + 3] = a.w;
    }
    __syncthreads();                               // b2

    // --- phase B: finalize l (in place) and scale W (in place) ---
    {
        float sb[8];
        #pragma unroll
        for (int tt = 0; tt < 8; ++tt) sb[tt] = sub[tt][m];
        float base_l = 0.f;
        #pragma unroll
        for (int tt = 0; tt < 8; ++tt) { if (tt < t) base_l += sb[tt]; }
        float es_own = 0.f;          // l at end of this group's sub-block (row (t|1)*4+3)
        const int tcap = t | 1;
        #pragma unroll
        for (int tt = 0; tt < 8; ++tt) { if (tt <= tcap) es_own += sb[tt]; }
        const float l0 = base_l + c0, l1 = base_l + c1,
                    l2 = base_l + c2, l3 = base_l + c3;
        l_s[r0 + 0][m] = l0; l_s[r0 + 1][m] = l1;
        l_s[r0 + 2][m] = l2; l_s[r0 + 3][m] = l3;
        // W = v * 2^{e_s - l}  (exponent <= 0)
        w_s[r0 + 0][m] *= fexp2(es_own - l0);
        w_s[r0 + 1][m] *= fexp2(es_own - l1);
        w_s[r0 + 2][m] *= fexp2(es_own - l2);
        w_s[r0 + 3][m] *= fexp2(es_own - l3);
    }
    __syncthreads();                               // b3

    // --- phase C: outputs ---
    const float4 val = *(float4*)&l_s[i][u];       // final l_i

    // cross-chunk: 2^{l_i} * (q_i . S0[:,m]) -- S0 straight from global
    const float* S0c = S0b + (long)(bh * NC + c) * (D * D);
    float4 o = {0, 0, 0, 0};
    #pragma unroll
    for (int dd = 0; dd < 8; ++dd) {
        float4 qd = *(float4*)&q_s[i][dd * 4];
        #pragma unroll
        for (int cc = 0; cc < 4; ++cc) {
            const float qv = (&qd.x)[cc];
            float4 s4 = *(const float4*)(S0c + (dd * 4 + cc) * D + u);
            o.x += qv * s4.x; o.y += qv * s4.y; o.z += qv * s4.z; o.w += qv * s4.w;
        }
    }
    o.x *= fexp2(val.x); o.y *= fexp2(val.y);
    o.z *= fexp2(val.z); o.w *= fexp2(val.w);

    // intra-chunk, sub-block factorized; e_s read from l_s rows 8s+7
    #pragma unroll
    for (int s2 = 0; s2 < 4; ++s2) {
        if (s2 <= wv) {
            float4 tc = {0, 0, 0, 0};
            if (s2 < wv) {
                #pragma unroll
                for (int jj = 0; jj < 8; ++jj) {
                    const float av = a_s[i][s2 * 8 + jj];
                    float4 w = *(float4*)&w_s[s2 * 8 + jj][u];
                    tc.x += av * w.x; tc.y += av * w.y;
                    tc.z += av * w.z; tc.w += av * w.w;
                }
            } else {
                #pragma unroll
                for (int jj = 0; jj < 8; ++jj) {
                    const int j = s2 * 8 + jj;
                    const float av = (j <= i) ? a_s[i][j] : 0.f;
                    float4 w = *(float4*)&w_s[j][u];
                    tc.x += av * w.x; tc.y += av * w.y;
                    tc.z += av * w.z; tc.w += av * w.w;
                }
            }
            float4 e4 = *(float4*)&l_s[s2 * 8 + 7][u];
            // s2<wv: exponent <= 0; s2==wv: in [0,112] -> finite
            o.x += fexp2(val.x - e4.x) * tc.x;
            o.y += fexp2(val.y - e4.y) * tc.y;
            o.z += fexp2(val.z - e4.z) * tc.z;
            o.w += fexp2(val.w - e4.w) * tc.w;
        }
    }

    *(float4*)(Op + roff) = o;
}

} // namespace

extern "C" void kernel_launch(void* const* d_in, const int* in_sizes, int n_in,
                              void* d_out, int out_size, void* d_ws, size_t ws_size,
                              hipStream_t stream)
{
    const float* q = (const float*)d_in[0];
    const float* k = (const float*)d_in[1];
    const float* v = (const float*)d_in[2];
    const float* g = (const float*)d_in[3];
    float* out = (float*)d_out;

    float* KVb = (float*)d_ws;                       // [NBH][NC][D][D]  (33.55 MB)
    float* Gb = KVb + (long)NBH * NC * D * D;        // [NBH][NC][D]     (1.05 MB)

    dim3 blk(256);
    k1_chunk_summary<<<dim3(NBH * NC), blk, 0, stream>>>(k, v, g, KVb, Gb);
    k2_scan<<<dim3(NBH * 4), blk, 0, stream>>>(KVb, Gb);
    k3_out<<<dim3(NBH * NC), blk, 0, stream>>>(q, k, v, g, KVb, out);
}

// Round 7
// 472.860 us; speedup vs baseline: 1.1111x; 1.1111x over previous
//
#include <hip/hip_runtime.h>

namespace {

constexpr int B = 4, S = 4096, H = 16, D = 32;
constexpr int L = 32;             // chunk length
constexpr int NC = S / L;         // 128 chunks per sequence
constexpr int NBH = B * H;        // 64
constexpr int RS = H * D;         // 512 floats between consecutive time steps
constexpr int PW = 36;            // padded LDS row width (16B-aligned rows, conflict-free)
constexpr float GEPS = 1.52587890625e-05f;  // 2^-16 per-step decay clamp
                                            // (max 7 steps to sub-block end * 16 = 112 < 126)

__device__ __forceinline__ float flog2(float x) { return __builtin_amdgcn_logf(x); }
__device__ __forceinline__ float fexp2(float x) { return __builtin_amdgcn_exp2f(x); }

// ---------------- Kernel 1: per-chunk summaries ----------------
// l = cumsum log2(max(g,GEPS)); W_j[m] = v_j[m]*2^{l_end[m]-l_j[m]} (<=1)
// KVb[bh][c][d][m] = sum_j k_j[d]*W_j[m];  Gb[bh][c][m] = 2^{l_end[m]}
// Scan: column-parallel in LDS (3 barriers, no shuffles -> low VGPR).
__global__ __launch_bounds__(256, 8)
void k1_chunk_summary(const float* __restrict__ Kp, const float* __restrict__ Vp,
                      const float* __restrict__ Gp, float* __restrict__ KVb,
                      float* __restrict__ Gb)
{
    __shared__ float k_s[L][PW];
    __shared__ float w_s[L][PW];   // v at load; scaled to W in place
    __shared__ float lg[L][PW];    // per-row log2(gate)
    __shared__ float sub[8][D];    // 4-row group subtotals

    const int blk = blockIdx.x;
    const int bh = blk / NC, c = blk % NC;
    const int b = bh / H, h = bh % H;
    const long base = ((long)b * S + (long)c * L) * RS + h * D;

    const int tid = threadIdx.x;
    const int i = tid >> 3;          // row 0..31
    const int u = (tid & 7) * 4;     // col quad
    const long roff = base + (long)i * RS + u;

    float4 k4 = *(const float4*)(Kp + roff);
    float4 v4 = *(const float4*)(Vp + roff);
    float4 g4 = *(const float4*)(Gp + roff);
    *(float4*)&k_s[i][u] = k4;
    *(float4*)&w_s[i][u] = v4;
    float4 lv;
    lv.x = flog2(fmaxf(g4.x, GEPS));
    lv.y = flog2(fmaxf(g4.y, GEPS));
    lv.z = flog2(fmaxf(g4.z, GEPS));
    lv.w = flog2(fmaxf(g4.w, GEPS));
    *(float4*)&lg[i][u] = lv;
    __syncthreads();                               // b1

    // column scan: thread -> (column m, 4-row group t)
    const int m = tid & 31, t = tid >> 5;
    const int r0 = t * 4;
    float c0 = lg[r0 + 0][m];
    float c1 = c0 + lg[r0 + 1][m];
    float c2 = c1 + lg[r0 + 2][m];
    float c3 = c2 + lg[r0 + 3][m];
    sub[t][m] = c3;
    __syncthreads();                               // b2

    float sb[8];
    float total = 0.f;
    #pragma unroll
    for (int tt = 0; tt < 8; ++tt) { sb[tt] = sub[tt][m]; total += sb[tt]; }
    float base_l = 0.f;
    #pragma unroll
    for (int tt = 0; tt < 8; ++tt) { if (tt < t) base_l += sb[tt]; }
    // W = v * 2^{total - l}   (exponent <= 0)
    w_s[r0 + 0][m] *= fexp2(total - (base_l + c0));
    w_s[r0 + 1][m] *= fexp2(total - (base_l + c1));
    w_s[r0 + 2][m] *= fexp2(total - (base_l + c2));
    w_s[r0 + 3][m] *= fexp2(total - (base_l + c3));
    if (t == 0) Gb[(long)(bh * NC + c) * D + m] = fexp2(total);
    __syncthreads();                               // b3

    // KV[d][m] = sum_j k[j][d] * W[j][m]
    const int d = tid >> 3;
    const int mg = (tid & 7) * 4;
    float4 acc = {0, 0, 0, 0};
    #pragma unroll
    for (int j = 0; j < L; ++j) {
        float kv = k_s[j][d];
        float4 w = *(float4*)&w_s[j][mg];
        acc.x += kv * w.x; acc.y += kv * w.y; acc.z += kv * w.z; acc.w += kv * w.w;
    }
    *(float4*)(KVb + (long)(bh * NC + c) * (D * D) + d * D + mg) = acc;
}

// ---------------- Kernel 2: inter-chunk scan (in-place KV -> S0) ----------------
// 8-deep batched prefetch; all register indices static.
__global__ __launch_bounds__(256)
void k2_scan(float* __restrict__ KVb, const float* __restrict__ Gb)
{
    const int bh = blockIdx.x >> 2;
    const int dg = blockIdx.x & 3;
    const int tid = threadIdx.x;
    const int d = dg * 8 + (tid >> 5);
    const int m = tid & 31;

    const long kvoff = (long)bh * NC * (D * D) + d * D + m;
    const long goff = (long)bh * NC * D + m;

    float ka[8], ga[8];
    #pragma unroll
    for (int t = 0; t < 8; ++t) {
        ka[t] = KVb[kvoff + (long)t * (D * D)];
        ga[t] = Gb[goff + (long)t * D];
    }
    float st = 0.f;
    for (int c0 = 0; c0 < NC; c0 += 8) {
        float kb[8], gb2[8];
        const bool more = (c0 + 8) < NC;
        #pragma unroll
        for (int t = 0; t < 8; ++t) {
            kb[t]  = more ? KVb[kvoff + (long)(c0 + 8 + t) * (D * D)] : 0.f;
            gb2[t] = more ? Gb[goff + (long)(c0 + 8 + t) * D] : 0.f;
        }
        #pragma unroll
        for (int t = 0; t < 8; ++t) {
            KVb[kvoff + (long)(c0 + t) * (D * D)] = st;   // chunk-START state
            st = ga[t] * st + ka[t];
        }
        #pragma unroll
        for (int t = 0; t < 8; ++t) { ka[t] = kb[t]; ga[t] = gb2[t]; }
    }
}

// ---------------- Kernel 3: per-chunk outputs ----------------
// out_i[m] = 2^{l_i[m]}*(q_i.S0[:,m])
//          + sum_{s<=si} 2^{l_i[m]-e_s[m]} * sum_{j in s, j<=i} A_ij*W_j[m]
// W_j[m] = v_j[m]*2^{e_{s(j)}[m]-l_j[m]};  e_s = l at row 8s+7 (sub-block end).
// 3 barriers. S0: ONE float4/thread global read at start, staged through LDS
// (overlaid on kT after the A-matmul) -- avoids the round-6 spill disaster.
__global__ __launch_bounds__(256, 6)
void k3_out(const float* __restrict__ Qp, const float* __restrict__ Kp,
            const float* __restrict__ Vp, const float* __restrict__ Gp,
            const float* __restrict__ S0b, float* __restrict__ Op)
{
    __shared__ float q_s[L][PW];
    __shared__ union KtS0 {               // kT dead after barrier b2 -> reuse for S0
        float kT[D][L + 1];
        float s0[D][PW];
    } kts;
    __shared__ float w_s[L][PW];   // v at load; scaled to W in place
    __shared__ float l_s[L][PW];   // logs at load; overwritten with final l
    __shared__ float a_s[L][L + 1];
    __shared__ float sub[8][D];

    const int blk = blockIdx.x;
    const int bh = blk / NC, c = blk % NC;
    const int b = bh / H, h = bh % H;
    const long base = ((long)b * S + (long)c * L) * RS + h * D;

    const int tid = threadIdx.x;
    const int i = tid >> 3;
    const int u = (tid & 7) * 4;
    const int wv = i >> 3;           // sub-block id (wave-uniform)
    const long roff = base + (long)i * RS + u;

    float4 q4 = *(const float4*)(Qp + roff);
    float4 k4 = *(const float4*)(Kp + roff);
    float4 v4 = *(const float4*)(Vp + roff);
    float4 g4 = *(const float4*)(Gp + roff);
    float4 s04 = *(const float4*)(S0b + (long)(bh * NC + c) * (D * D) + tid * 4);

    *(float4*)&q_s[i][u] = q4;
    kts.kT[u + 0][i] = k4.x; kts.kT[u + 1][i] = k4.y;
    kts.kT[u + 2][i] = k4.z; kts.kT[u + 3][i] = k4.w;
    *(float4*)&w_s[i][u] = v4;
    float4 lv;
    lv.x = flog2(fmaxf(g4.x, GEPS));
    lv.y = flog2(fmaxf(g4.y, GEPS));
    lv.z = flog2(fmaxf(g4.z, GEPS));
    lv.w = flog2(fmaxf(g4.w, GEPS));
    *(float4*)&l_s[i][u] = lv;
    __syncthreads();                               // b1

    // --- phase A: column subtotals + A-matmul (independent work) ---
    const int m = tid & 31, t = tid >> 5;
    const int r0 = t * 4;
    float c0 = l_s[r0 + 0][m];
    float c1 = c0 + l_s[r0 + 1][m];
    float c2 = c1 + l_s[r0 + 2][m];
    float c3 = c2 + l_s[r0 + 3][m];
    sub[t][m] = c3;

    // A[i][u..u+3] = q_i . k_j (unmasked; consumers use j<=i only)
    {
        float4 a = {0, 0, 0, 0};
        #pragma unroll
        for (int dd = 0; dd < 8; ++dd) {
            float4 qd = *(float4*)&q_s[i][dd * 4];
            #pragma unroll
            for (int cc = 0; cc < 4; ++cc) {
                const float qv = (&qd.x)[cc];
                const int d = dd * 4 + cc;
                a.x += qv * kts.kT[d][u + 0];
                a.y += qv * kts.kT[d][u + 1];
                a.z += qv * kts.kT[d][u + 2];
                a.w += qv * kts.kT[d][u + 3];
            }
        }
        a_s[i][u + 0] = a.x; a_s[i][u + 1] = a.y;
        a_s[i][u + 2] = a.z; a_s[i][u + 3] = a.w;
    }
    __syncthreads();                               // b2  (kT dead from here)

    // --- phase B: finalize l (in place), scale W (in place), stage S0 ---
    {
        float sb[8];
        #pragma unroll
        for (int tt = 0; tt < 8; ++tt) sb[tt] = sub[tt][m];
        float base_l = 0.f;
        #pragma unroll
        for (int tt = 0; tt < 8; ++tt) { if (tt < t) base_l += sb[tt]; }
        float es_own = 0.f;          // l at end of this group's sub-block (row (t|1)*4+3)
        const int tcap = t | 1;
        #pragma unroll
        for (int tt = 0; tt < 8; ++tt) { if (tt <= tcap) es_own += sb[tt]; }
        const float l0 = base_l + c0, l1 = base_l + c1,
                    l2 = base_l + c2, l3 = base_l + c3;
        l_s[r0 + 0][m] = l0; l_s[r0 + 1][m] = l1;
        l_s[r0 + 2][m] = l2; l_s[r0 + 3][m] = l3;
        // W = v * 2^{e_s - l}  (exponent <= 0)
        w_s[r0 + 0][m] *= fexp2(es_own - l0);
        w_s[r0 + 1][m] *= fexp2(es_own - l1);
        w_s[r0 + 2][m] *= fexp2(es_own - l2);
        w_s[r0 + 3][m] *= fexp2(es_own - l3);
    }
    *(float4*)&kts.s0[tid >> 3][(tid & 7) * 4] = s04;   // stage S0 into old kT slot
    __syncthreads();                               // b3

    // --- phase C: outputs ---
    const float4 val = *(float4*)&l_s[i][u];       // final l_i

    // cross-chunk: 2^{l_i} * (q_i . S0[:,m])
    float4 o = {0, 0, 0, 0};
    #pragma unroll
    for (int dd = 0; dd < 8; ++dd) {
        float4 qd = *(float4*)&q_s[i][dd * 4];
        #pragma unroll
        for (int cc = 0; cc < 4; ++cc) {
            const float qv = (&qd.x)[cc];
            float4 s4 = *(float4*)&kts.s0[dd * 4 + cc][u];
            o.x += qv * s4.x; o.y += qv * s4.y; o.z += qv * s4.z; o.w += qv * s4.w;
        }
    }
    o.x *= fexp2(val.x); o.y *= fexp2(val.y);
    o.z *= fexp2(val.z); o.w *= fexp2(val.w);

    // intra-chunk, sub-block factorized; e_s read from l_s rows 8s+7
    #pragma unroll
    for (int s2 = 0; s2 < 4; ++s2) {
        if (s2 <= wv) {
            float4 tc = {0, 0, 0, 0};
            if (s2 < wv) {
                #pragma unroll
                for (int jj = 0; jj < 8; ++jj) {
                    const float av = a_s[i][s2 * 8 + jj];
                    float4 w = *(float4*)&w_s[s2 * 8 + jj][u];
                    tc.x += av * w.x; tc.y += av * w.y;
                    tc.z += av * w.z; tc.w += av * w.w;
                }
            } else {
                #pragma unroll
                for (int jj = 0; jj < 8; ++jj) {
                    const int j = s2 * 8 + jj;
                    const float av = (j <= i) ? a_s[i][j] : 0.f;
                    float4 w = *(float4*)&w_s[j][u];
                    tc.x += av * w.x; tc.y += av * w.y;
                    tc.z += av * w.z; tc.w += av * w.w;
                }
            }
            float4 e4 = *(float4*)&l_s[s2 * 8 + 7][u];
            // s2<wv: exponent <= 0; s2==wv: in [0,112] -> finite
            o.x += fexp2(val.x - e4.x) * tc.x;
            o.y += fexp2(val.y - e4.y) * tc.y;
            o.z += fexp2(val.z - e4.z) * tc.z;
            o.w += fexp2(val.w - e4.w) * tc.w;
        }
    }

    *(float4*)(Op + roff) = o;
}

} // namespace

extern "C" void kernel_launch(void* const* d_in, const int* in_sizes, int n_in,
                              void* d_out, int out_size, void* d_ws, size_t ws_size,
                              hipStream_t stream)
{
    const float* q = (const float*)d_in[0];
    const float* k = (const float*)d_in[1];
    const float* v = (const float*)d_in[2];
    const float* g = (const float*)d_in[3];
    float* out = (float*)d_out;

    float* KVb = (float*)d_ws;                       // [NBH][NC][D][D]  (33.55 MB)
    float* Gb = KVb + (long)NBH * NC * D * D;        // [NBH][NC][D]     (1.05 MB)

    dim3 blk(256);
    k1_chunk_summary<<<dim3(NBH * NC), blk, 0, stream>>>(k, v, g, KVb, Gb);
    k2_scan<<<dim3(NBH * 4), blk, 0, stream>>>(KVb, Gb);
    k3_out<<<dim3(NBH * NC), blk, 0, stream>>>(q, k, v, g, KVb, out);
}

// Round 8
// 108.197 us; speedup vs baseline: 4.8557x; 4.3704x over previous
//
#include <hip/hip_runtime.h>

namespace {

constexpr int B = 4, S = 4096, H = 16, D = 32;
constexpr int L = 32;             // chunk length
constexpr int NC = S / L;         // 128 chunks per sequence
constexpr int NBH = B * H;        // 64
constexpr int RS = H * D;         // 512 floats between consecutive time steps
constexpr int PW = 36;            // padded LDS row width (16B-aligned rows, conflict-free)
constexpr float GEPS = 1.52587890625e-05f;  // 2^-16 per-step decay clamp
                                            // (max 7 steps to sub-block end * 16 = 112 < 126)

// NOTE (gfx950 hipcc): __launch_bounds__(B, w) caps VGPRs at 256/w.
// w>=6 strangled k3 to 36-40 VGPRs -> ~1.1 GB scratch spill (rounds 6-7).
// Use plain __launch_bounds__(256) and let the allocator choose.

__device__ __forceinline__ float flog2(float x) { return __builtin_amdgcn_logf(x); }
__device__ __forceinline__ float fexp2(float x) { return __builtin_amdgcn_exp2f(x); }

// ---------------- Kernel 1: per-chunk summaries ----------------
// l = cumsum log2(max(g,GEPS)); W_j[m] = v_j[m]*2^{l_end[m]-l_j[m]} (<=1)
// KVb[bh][c][d][m] = sum_j k_j[d]*W_j[m];  Gb[bh][c][m] = 2^{l_end[m]}
// Scan: column-parallel in LDS (3 barriers, no shuffles -> low VGPR).
__global__ __launch_bounds__(256)
void k1_chunk_summary(const float* __restrict__ Kp, const float* __restrict__ Vp,
                      const float* __restrict__ Gp, float* __restrict__ KVb,
                      float* __restrict__ Gb)
{
    __shared__ float k_s[L][PW];
    __shared__ float w_s[L][PW];   // v at load; scaled to W in place
    __shared__ float lg[L][PW];    // per-row log2(gate)
    __shared__ float sub[8][D];    // 4-row group subtotals

    const int blk = blockIdx.x;
    const int bh = blk / NC, c = blk % NC;
    const int b = bh / H, h = bh % H;
    const long base = ((long)b * S + (long)c * L) * RS + h * D;

    const int tid = threadIdx.x;
    const int i = tid >> 3;          // row 0..31
    const int u = (tid & 7) * 4;     // col quad
    const long roff = base + (long)i * RS + u;

    float4 k4 = *(const float4*)(Kp + roff);
    float4 v4 = *(const float4*)(Vp + roff);
    float4 g4 = *(const float4*)(Gp + roff);
    *(float4*)&k_s[i][u] = k4;
    *(float4*)&w_s[i][u] = v4;
    float4 lv;
    lv.x = flog2(fmaxf(g4.x, GEPS));
    lv.y = flog2(fmaxf(g4.y, GEPS));
    lv.z = flog2(fmaxf(g4.z, GEPS));
    lv.w = flog2(fmaxf(g4.w, GEPS));
    *(float4*)&lg[i][u] = lv;
    __syncthreads();                               // b1

    // column scan: thread -> (column m, 4-row group t)
    const int m = tid & 31, t = tid >> 5;
    const int r0 = t * 4;
    float c0 = lg[r0 + 0][m];
    float c1 = c0 + lg[r0 + 1][m];
    float c2 = c1 + lg[r0 + 2][m];
    float c3 = c2 + lg[r0 + 3][m];
    sub[t][m] = c3;
    __syncthreads();                               // b2

    float sb[8];
    float total = 0.f;
    #pragma unroll
    for (int tt = 0; tt < 8; ++tt) { sb[tt] = sub[tt][m]; total += sb[tt]; }
    float base_l = 0.f;
    #pragma unroll
    for (int tt = 0; tt < 8; ++tt) { if (tt < t) base_l += sb[tt]; }
    // W = v * 2^{total - l}   (exponent <= 0)
    w_s[r0 + 0][m] *= fexp2(total - (base_l + c0));
    w_s[r0 + 1][m] *= fexp2(total - (base_l + c1));
    w_s[r0 + 2][m] *= fexp2(total - (base_l + c2));
    w_s[r0 + 3][m] *= fexp2(total - (base_l + c3));
    if (t == 0) Gb[(long)(bh * NC + c) * D + m] = fexp2(total);
    __syncthreads();                               // b3

    // KV[d][m] = sum_j k[j][d] * W[j][m]
    const int d = tid >> 3;
    const int mg = (tid & 7) * 4;
    float4 acc = {0, 0, 0, 0};
    #pragma unroll
    for (int j = 0; j < L; ++j) {
        float kv = k_s[j][d];
        float4 w = *(float4*)&w_s[j][mg];
        acc.x += kv * w.x; acc.y += kv * w.y; acc.z += kv * w.z; acc.w += kv * w.w;
    }
    *(float4*)(KVb + (long)(bh * NC + c) * (D * D) + d * D + mg) = acc;
}

// ---------------- Kernel 2: inter-chunk scan (in-place KV -> S0) ----------------
// 8-deep batched prefetch; all register indices static.
__global__ __launch_bounds__(256)
void k2_scan(float* __restrict__ KVb, const float* __restrict__ Gb)
{
    const int bh = blockIdx.x >> 2;
    const int dg = blockIdx.x & 3;
    const int tid = threadIdx.x;
    const int d = dg * 8 + (tid >> 5);
    const int m = tid & 31;

    const long kvoff = (long)bh * NC * (D * D) + d * D + m;
    const long goff = (long)bh * NC * D + m;

    float ka[8], ga[8];
    #pragma unroll
    for (int t = 0; t < 8; ++t) {
        ka[t] = KVb[kvoff + (long)t * (D * D)];
        ga[t] = Gb[goff + (long)t * D];
    }
    float st = 0.f;
    for (int c0 = 0; c0 < NC; c0 += 8) {
        float kb[8], gb2[8];
        const bool more = (c0 + 8) < NC;
        #pragma unroll
        for (int t = 0; t < 8; ++t) {
            kb[t]  = more ? KVb[kvoff + (long)(c0 + 8 + t) * (D * D)] : 0.f;
            gb2[t] = more ? Gb[goff + (long)(c0 + 8 + t) * D] : 0.f;
        }
        #pragma unroll
        for (int t = 0; t < 8; ++t) {
            KVb[kvoff + (long)(c0 + t) * (D * D)] = st;   // chunk-START state
            st = ga[t] * st + ka[t];
        }
        #pragma unroll
        for (int t = 0; t < 8; ++t) { ka[t] = kb[t]; ga[t] = gb2[t]; }
    }
}

// ---------------- Kernel 3: per-chunk outputs ----------------
// out_i[m] = 2^{l_i[m]}*(q_i.S0[:,m])
//          + sum_{s<=si} 2^{l_i[m]-e_s[m]} * sum_{j in s, j<=i} A_ij*W_j[m]
// W_j[m] = v_j[m]*2^{e_{s(j)}[m]-l_j[m]};  e_s = l at row 8s+7 (sub-block end).
// 3 barriers. S0: one float4/thread global read at start, staged into the
// kT LDS slot after the A-matmul no longer needs it (union overlay).
__global__ __launch_bounds__(256)
void k3_out(const float* __restrict__ Qp, const float* __restrict__ Kp,
            const float* __restrict__ Vp, const float* __restrict__ Gp,
            const float* __restrict__ S0b, float* __restrict__ Op)
{
    __shared__ float q_s[L][PW];
    __shared__ union KtS0 {               // kT dead after barrier b2 -> reuse for S0
        float kT[D][L + 1];
        float s0[D][PW];
    } kts;
    __shared__ float w_s[L][PW];   // v at load; scaled to W in place
    __shared__ float l_s[L][PW];   // logs at load; overwritten with final l
    __shared__ float a_s[L][L + 1];
    __shared__ float sub[8][D];

    const int blk = blockIdx.x;
    const int bh = blk / NC, c = blk % NC;
    const int b = bh / H, h = bh % H;
    const long base = ((long)b * S + (long)c * L) * RS + h * D;

    const int tid = threadIdx.x;
    const int i = tid >> 3;
    const int u = (tid & 7) * 4;
    const int wv = i >> 3;           // sub-block id (wave-uniform)
    const long roff = base + (long)i * RS + u;

    float4 q4 = *(const float4*)(Qp + roff);
    float4 k4 = *(const float4*)(Kp + roff);
    float4 v4 = *(const float4*)(Vp + roff);
    float4 g4 = *(const float4*)(Gp + roff);
    float4 s04 = *(const float4*)(S0b + (long)(bh * NC + c) * (D * D) + tid * 4);

    *(float4*)&q_s[i][u] = q4;
    kts.kT[u + 0][i] = k4.x; kts.kT[u + 1][i] = k4.y;
    kts.kT[u + 2][i] = k4.z; kts.kT[u + 3][i] = k4.w;
    *(float4*)&w_s[i][u] = v4;
    float4 lv;
    lv.x = flog2(fmaxf(g4.x, GEPS));
    lv.y = flog2(fmaxf(g4.y, GEPS));
    lv.z = flog2(fmaxf(g4.z, GEPS));
    lv.w = flog2(fmaxf(g4.w, GEPS));
    *(float4*)&l_s[i][u] = lv;
    __syncthreads();                               // b1

    // --- phase A: column subtotals + A-matmul (independent work) ---
    const int m = tid & 31, t = tid >> 5;
    const int r0 = t * 4;
    float c0 = l_s[r0 + 0][m];
    float c1 = c0 + l_s[r0 + 1][m];
    float c2 = c1 + l_s[r0 + 2][m];
    float c3 = c2 + l_s[r0 + 3][m];
    sub[t][m] = c3;

    // A[i][u..u+3] = q_i . k_j (unmasked; consumers use j<=i only)
    {
        float4 a = {0, 0, 0, 0};
        #pragma unroll
        for (int dd = 0; dd < 8; ++dd) {
            float4 qd = *(float4*)&q_s[i][dd * 4];
            #pragma unroll
            for (int cc = 0; cc < 4; ++cc) {
                const float qv = (&qd.x)[cc];
                const int d = dd * 4 + cc;
                a.x += qv * kts.kT[d][u + 0];
                a.y += qv * kts.kT[d][u + 1];
                a.z += qv * kts.kT[d][u + 2];
                a.w += qv * kts.kT[d][u + 3];
            }
        }
        a_s[i][u + 0] = a.x; a_s[i][u + 1] = a.y;
        a_s[i][u + 2] = a.z; a_s[i][u + 3] = a.w;
    }
    __syncthreads();                               // b2  (kT dead from here)

    // --- phase B: finalize l (in place), scale W (in place), stage S0 ---
    {
        float sb[8];
        #pragma unroll
        for (int tt = 0; tt < 8; ++tt) sb[tt] = sub[tt][m];
        float base_l = 0.f;
        #pragma unroll
        for (int tt = 0; tt < 8; ++tt) { if (tt < t) base_l += sb[tt]; }
        float es_own = 0.f;          // l at end of this group's sub-block (row (t|1)*4+3)
        const int tcap = t | 1;
        #pragma unroll
        for (int tt = 0; tt < 8; ++tt) { if (tt <= tcap) es_own += sb[tt]; }
        const float l0 = base_l + c0, l1 = base_l + c1,
                    l2 = base_l + c2, l3 = base_l + c3;
        l_s[r0 + 0][m] = l0; l_s[r0 + 1][m] = l1;
        l_s[r0 + 2][m] = l2; l_s[r0 + 3][m] = l3;
        // W = v * 2^{e_s - l}  (exponent <= 0)
        w_s[r0 + 0][m] *= fexp2(es_own - l0);
        w_s[r0 + 1][m] *= fexp2(es_own - l1);
        w_s[r0 + 2][m] *= fexp2(es_own - l2);
        w_s[r0 + 3][m] *= fexp2(es_own - l3);
    }
    *(float4*)&kts.s0[tid >> 3][(tid & 7) * 4] = s04;   // stage S0 into old kT slot
    __syncthreads();                               // b3

    // --- phase C: outputs ---
    const float4 val = *(float4*)&l_s[i][u];       // final l_i

    // cross-chunk: 2^{l_i} * (q_i . S0[:,m])
    float4 o = {0, 0, 0, 0};
    #pragma unroll
    for (int dd = 0; dd < 8; ++dd) {
        float4 qd = *(float4*)&q_s[i][dd * 4];
        #pragma unroll
        for (int cc = 0; cc < 4; ++cc) {
            const float qv = (&qd.x)[cc];
            float4 s4 = *(float4*)&kts.s0[dd * 4 + cc][u];
            o.x += qv * s4.x; o.y += qv * s4.y; o.z += qv * s4.z; o.w += qv * s4.w;
        }
    }
    o.x *= fexp2(val.x); o.y *= fexp2(val.y);
    o.z *= fexp2(val.z); o.w *= fexp2(val.w);

    // intra-chunk, sub-block factorized; e_s read from l_s rows 8s+7
    #pragma unroll
    for (int s2 = 0; s2 < 4; ++s2) {
        if (s2 <= wv) {
            float4 tc = {0, 0, 0, 0};
            if (s2 < wv) {
                #pragma unroll
                for (int jj = 0; jj < 8; ++jj) {
                    const float av = a_s[i][s2 * 8 + jj];
                    float4 w = *(float4*)&w_s[s2 * 8 + jj][u];
                    tc.x += av * w.x; tc.y += av * w.y;
                    tc.z += av * w.z; tc.w += av * w.w;
                }
            } else {
                #pragma unroll
                for (int jj = 0; jj < 8; ++jj) {
                    const int j = s2 * 8 + jj;
                    const float av = (j <= i) ? a_s[i][j] : 0.f;
                    float4 w = *(float4*)&w_s[j][u];
                    tc.x += av * w.x; tc.y += av * w.y;
                    tc.z += av * w.z; tc.w += av * w.w;
                }
            }
            float4 e4 = *(float4*)&l_s[s2 * 8 + 7][u];
            // s2<wv: exponent <= 0; s2==wv: in [0,112] -> finite
            o.x += fexp2(val.x - e4.x) * tc.x;
            o.y += fexp2(val.y - e4.y) * tc.y;
            o.z += fexp2(val.z - e4.z) * tc.z;
            o.w += fexp2(val.w - e4.w) * tc.w;
        }
    }

    *(float4*)(Op + roff) = o;
}

} // namespace

extern "C" void kernel_launch(void* const* d_in, const int* in_sizes, int n_in,
                              void* d_out, int out_size, void* d_ws, size_t ws_size,
                              hipStream_t stream)
{
    const float* q = (const float*)d_in[0];
    const float* k = (const float*)d_in[1];
    const float* v = (const float*)d_in[2];
    const float* g = (const float*)d_in[3];
    float* out = (float*)d_out;

    float* KVb = (float*)d_ws;                       // [NBH][NC][D][D]  (33.55 MB)
    float* Gb = KVb + (long)NBH * NC * D * D;        // [NBH][NC][D]     (1.05 MB)

    dim3 blk(256);
    k1_chunk_summary<<<dim3(NBH * NC), blk, 0, stream>>>(k, v, g, KVb, Gb);
    k2_scan<<<dim3(NBH * 4), blk, 0, stream>>>(KVb, Gb);
    k3_out<<<dim3(NBH * NC), blk, 0, stream>>>(q, k, v, g, KVb, out);
}